// Round 4
// baseline (588.318 us; speedup 1.0000x reference)
//
#include <hip/hip_runtime.h>
#include <hip/hip_bf16.h>

// BLSTM: B=1024, T=512, V=128, H=128, HH=64, gates=256/dir.
// R4: gate-permuted tiles (each wave owns all 4 LSTM gates for its 8 hidden
// units) -> combine via 4 shfl_xor(8), no gates-LDS, ONE barrier/step with
// ping-pong h buffer laid out in exact A-fragment order (conflict-free b128).
// ws: tab f32[2][128][256] (permuted cols) ; whh_hi/lo u16[2][256][64] ; hfin.

#define T_STEPS 512
#define BATCH   1024
#define VOCAB   128
#define HID     128
#define HH      64
#define NG      256
#define MB      8      // real batch rows per block

typedef __attribute__((ext_vector_type(8))) short bf16x8;
typedef __attribute__((ext_vector_type(4))) float f32x4;
typedef unsigned int  u32;
typedef unsigned short u16;

__device__ __forceinline__ float sigmoid_f(float x) {
    return 1.0f / (1.0f + __expf(-x));
}
__device__ __forceinline__ float tanh_f(float x) {
    return 1.0f - 2.0f / (__expf(2.0f * x) + 1.0f);
}
__device__ __forceinline__ u16 f2bf(float f) {
    u32 u = __builtin_bit_cast(u32, f);
    u += 0x7FFFu + ((u >> 16) & 1u);
    return (u16)(u >> 16);
}
__device__ __forceinline__ float bf2f(u16 b) {
    return __builtin_bit_cast(float, ((u32)b) << 16);
}

// permuted gate column c (0..255) -> original gate row g
// c = tile*128 + w*16 + m ; m<8 -> gate (tile?2:0), j=w*8+m ; m>=8 -> gate+1, j=w*8+m-8
__device__ __forceinline__ int perm_gate(int c) {
    int tile = c >> 7, rest = c & 127, w = rest >> 4, m = rest & 15;
    return (m < 8) ? (tile * 128 + w * 8 + m)
                   : (tile * 128 + 64 + w * 8 + (m - 8));
}

// ---------------- Kernel 1: input-projection tables (permuted cols) -------
__global__ __launch_bounds__(256) void build_tab_kernel(
    const float* __restrict__ emb,
    const float* __restrict__ W_ih_f,
    const float* __restrict__ W_ih_b,
    float* __restrict__ tab)
{
    int v = blockIdx.x, d = blockIdx.y, gp = threadIdx.x;
    int g = perm_gate(gp);
    const float* W = d ? W_ih_b : W_ih_f;
    const float4* e4 = (const float4*)(emb + v * HID);
    const float4* w4 = (const float4*)(W + g * HID);
    float acc = 0.0f;
#pragma unroll
    for (int k = 0; k < HID / 4; ++k) {
        float4 e = e4[k]; float4 w = w4[k];
        acc += e.x * w.x + e.y * w.y + e.z * w.z + e.w * w.w;
    }
    tab[(d * VOCAB + v) * NG + gp] = acc;
}

// ---------------- Kernel 1b: split W_hh into bf16 hi/lo (orig order) ------
__global__ __launch_bounds__(64) void split_whh_kernel(
    const float* __restrict__ W_hh_f,
    const float* __restrict__ W_hh_b,
    u16* __restrict__ whh_hi,
    u16* __restrict__ whh_lo)
{
    int g = blockIdx.x, d = blockIdx.y, k = threadIdx.x;
    const float* W = d ? W_hh_b : W_hh_f;
    float w = W[g * HH + k];
    u16 hb = f2bf(w);
    u16 lb = f2bf(w - bf2f(hb));
    whh_hi[(d * NG + g) * HH + k] = hb;
    whh_lo[(d * NG + g) * HH + k] = lb;
}

// ---------------- Kernel 2: MFMA recurrence ----------------
// grid (128,2), block 512 (8 waves), 1 block/CU.
// h layout (per buffer): elem(m,k) = (k>>5)*512 + ((k>>3)&3)*128 + m*8 + (k&7)
//   -> lane l reads its A-frag at byte addr l*16 (+1024 for kc=1): 0 conflicts.
__global__ __launch_bounds__(512, 2) void lstm_rec_kernel(
    const int*  __restrict__ x,        // [1024][512]
    const u16*  __restrict__ whh_hi,   // [2][256][64] bf16 bits (orig gate order)
    const u16*  __restrict__ whh_lo,
    const float* __restrict__ tab,     // [2][128][256] permuted cols
    float* __restrict__ hfin)          // [2][1024][64]
{
    __shared__ int xs[T_STEPS][MB];      // 16 KB
    __shared__ u16 hbuf[2][2][1024];     // [pingpong][hi/lo][elem] 8 KB

    const int tid  = threadIdx.x;
    const int lane = tid & 63;
    const int wave = tid >> 6;           // 0..7
    const int quad = lane >> 4;          // 0..3
    const int m    = lane & 15;
    const int dir    = blockIdx.y;
    const int b_base = blockIdx.x * MB;

    // stage x
    for (int i = tid; i < MB * T_STEPS; i += 512) {
        int bl = i >> 9, t = i & (T_STEPS - 1);
        xs[t][bl] = x[(b_base + bl) * T_STEPS + t];
    }
    // zero both h buffers
    for (int i = tid; i < 2048; i += 512) ((u32*)hbuf)[i] = 0;

    // persistent B-fragments, permuted gate rows
    const u16* WH = whh_hi + dir * NG * HH;
    const u16* WL = whh_lo + dir * NG * HH;
    bf16x8 Bh[2][2], Bl[2][2];
#pragma unroll
    for (int tile = 0; tile < 2; ++tile) {
        int grow = perm_gate(tile * 128 + wave * 16 + m);
#pragma unroll
        for (int kc = 0; kc < 2; ++kc) {
            Bh[tile][kc] = *(const bf16x8*)(WH + grow * HH + kc * 32 + quad * 8);
            Bl[tile][kc] = *(const bf16x8*)(WL + grow * HH + kc * 32 + quad * 8);
        }
    }

    const float* tabD = tab + dir * VOCAB * NG;
    const int  c0      = wave * 16 + m;
    const bool lohalf  = (m < 8);
    const int  rb      = lohalf ? 0 : 2;         // C rows this lane finalizes
    const int  bA      = quad * 4 + rb;          // first of 2 batch rows
    const int  wbase   = (wave >> 2) * 512 + (wave & 3) * 128 + (m & 7);
    const int  aoff    = lane * 8;               // u16 units

    float cA = 0.f, cB = 0.f, hA = 0.f, hB = 0.f;

    __syncthreads();   // xs + hbuf init visible

    float init0[4], init1[4], next0[4], next1[4];
    {
        int t0 = dir ? (T_STEPS - 1) : 0;
#pragma unroll
        for (int r = 0; r < 4; ++r) {
            int v = xs[t0][(quad * 4 + r) & 7];
            init0[r] = tabD[v * NG + c0];
            init1[r] = tabD[v * NG + c0 + 128];
        }
    }

    for (int s = 0; s < T_STEPS; ++s) {
        const u16* hb = hbuf[s & 1][0];
        const u16* lb = hbuf[s & 1][1];
        bf16x8 Ah0 = *(const bf16x8*)(hb + aoff);
        bf16x8 Ah1 = *(const bf16x8*)(hb + 512 + aoff);
        bf16x8 Al0 = *(const bf16x8*)(lb + aoff);
        bf16x8 Al1 = *(const bf16x8*)(lb + 512 + aoff);

        f32x4 acc0 = {init0[0], init0[1], init0[2], init0[3]};
        f32x4 acc1 = {init1[0], init1[1], init1[2], init1[3]};
        acc0 = __builtin_amdgcn_mfma_f32_16x16x32_bf16(Ah0, Bh[0][0], acc0, 0, 0, 0);
        acc1 = __builtin_amdgcn_mfma_f32_16x16x32_bf16(Ah0, Bh[1][0], acc1, 0, 0, 0);
        acc0 = __builtin_amdgcn_mfma_f32_16x16x32_bf16(Ah1, Bh[0][1], acc0, 0, 0, 0);
        acc1 = __builtin_amdgcn_mfma_f32_16x16x32_bf16(Ah1, Bh[1][1], acc1, 0, 0, 0);
        acc0 = __builtin_amdgcn_mfma_f32_16x16x32_bf16(Al0, Bh[0][0], acc0, 0, 0, 0);
        acc1 = __builtin_amdgcn_mfma_f32_16x16x32_bf16(Al0, Bh[1][0], acc1, 0, 0, 0);
        acc0 = __builtin_amdgcn_mfma_f32_16x16x32_bf16(Al1, Bh[0][1], acc0, 0, 0, 0);
        acc1 = __builtin_amdgcn_mfma_f32_16x16x32_bf16(Al1, Bh[1][1], acc1, 0, 0, 0);
        acc0 = __builtin_amdgcn_mfma_f32_16x16x32_bf16(Ah0, Bl[0][0], acc0, 0, 0, 0);
        acc1 = __builtin_amdgcn_mfma_f32_16x16x32_bf16(Ah0, Bl[1][0], acc1, 0, 0, 0);
        acc0 = __builtin_amdgcn_mfma_f32_16x16x32_bf16(Ah1, Bl[0][1], acc0, 0, 0, 0);
        acc1 = __builtin_amdgcn_mfma_f32_16x16x32_bf16(Ah1, Bl[1][1], acc1, 0, 0, 0);

        // prefetch next-step tab init (overlaps phase B + barrier)
        {
            int sn = (s + 1 < T_STEPS) ? s + 1 : s;
            int tn = dir ? (T_STEPS - 1 - sn) : sn;
#pragma unroll
            for (int r = 0; r < 4; ++r) {
                int v = xs[tn][(quad * 4 + r) & 7];
                next0[r] = tabD[v * NG + c0];
                next1[r] = tabD[v * NG + c0 + 128];
            }
        }

        // in-wave gate exchange: partner = lane ^ 8 (same quad)
        float e0 = __shfl_xor(lohalf ? acc0[2] : acc0[0], 8);
        float e1 = __shfl_xor(lohalf ? acc0[3] : acc0[1], 8);
        float e2 = __shfl_xor(lohalf ? acc1[2] : acc1[0], 8);
        float e3 = __shfl_xor(lohalf ? acc1[3] : acc1[1], 8);

        float i0 = lohalf ? acc0[0] : e0;
        float f0 = lohalf ? e0 : acc0[2];
        float g0 = lohalf ? acc1[0] : e2;
        float o0 = lohalf ? e2 : acc1[2];
        float i1 = lohalf ? acc0[1] : e1;
        float f1 = lohalf ? e1 : acc0[3];
        float g1 = lohalf ? acc1[1] : e3;
        float o1 = lohalf ? e3 : acc1[3];

        cA = sigmoid_f(f0) * cA + sigmoid_f(i0) * tanh_f(g0);
        hA = sigmoid_f(o0) * tanh_f(cA);
        cB = sigmoid_f(f1) * cB + sigmoid_f(i1) * tanh_f(g1);
        hB = sigmoid_f(o1) * tanh_f(cB);

        u16* dh = hbuf[(s + 1) & 1][0];
        u16* dl = hbuf[(s + 1) & 1][1];
        u16 hAh = f2bf(hA); u16 hAl = f2bf(hA - bf2f(hAh));
        u16 hBh = f2bf(hB); u16 hBl = f2bf(hB - bf2f(hBh));
        dh[wbase + bA * 8]       = hAh;
        dl[wbase + bA * 8]       = hAl;
        dh[wbase + (bA + 1) * 8] = hBh;
        dl[wbase + (bA + 1) * 8] = hBl;

#pragma unroll
        for (int r = 0; r < 4; ++r) { init0[r] = next0[r]; init1[r] = next1[r]; }

        __syncthreads();   // single barrier: h[(s+1)&1] complete for next step
    }

    if (bA < 8) {   // real batch rows only (quad 0,1)
        int j = wave * 8 + (m & 7);
        hfin[(dir * BATCH + b_base + bA) * HH + j]     = hA;
        hfin[(dir * BATCH + b_base + bA + 1) * HH + j] = hB;
    }
}

// ---------------- Kernel 3: final FC ----------------
__global__ __launch_bounds__(128) void fc_kernel(
    const float* __restrict__ hfin,
    const float* __restrict__ W_fc,
    const float* __restrict__ b_fc,
    float* __restrict__ out)
{
    int b = blockIdx.x;
    int v = threadIdx.x;
    __shared__ float hid[HID];
    if (v < HH) hid[v] = hfin[(0 * BATCH + b) * HH + v];
    else        hid[v] = hfin[(1 * BATCH + b) * HH + (v - HH)];
    __syncthreads();
    const float4* w4 = (const float4*)(W_fc + v * HID);
    const float4* h4 = (const float4*)hid;
    float acc = b_fc[v];
#pragma unroll
    for (int k = 0; k < HID / 4; ++k) {
        float4 w = w4[k]; float4 h = h4[k];
        acc += w.x * h.x + w.y * h.y + w.z * h.z + w.w * h.w;
    }
    out[b * HID + v] = acc;
}

extern "C" void kernel_launch(void* const* d_in, const int* in_sizes, int n_in,
                              void* d_out, int out_size, void* d_ws, size_t ws_size,
                              hipStream_t stream) {
    const int*   x      = (const int*)d_in[0];
    // d_in[1] = lengths : unused by the reference
    const float* emb    = (const float*)d_in[2];
    const float* W_ih_f = (const float*)d_in[3];
    const float* W_hh_f = (const float*)d_in[4];
    const float* W_ih_b = (const float*)d_in[5];
    const float* W_hh_b = (const float*)d_in[6];
    const float* W_fc   = (const float*)d_in[7];
    const float* b_fc   = (const float*)d_in[8];
    float* out = (float*)d_out;

    float* tab    = (float*)d_ws;                         // 65536 f32
    u16*   whh_hi = (u16*)(tab + 2 * VOCAB * NG);         // 32768 u16
    u16*   whh_lo = whh_hi + 2 * NG * HH;                 // 32768 u16
    float* hfin   = (float*)(whh_lo + 2 * NG * HH);       // 131072 f32

    build_tab_kernel<<<dim3(VOCAB, 2), 256, 0, stream>>>(emb, W_ih_f, W_ih_b, tab);
    split_whh_kernel<<<dim3(NG, 2), 64, 0, stream>>>(W_hh_f, W_hh_b, whh_hi, whh_lo);
    lstm_rec_kernel<<<dim3(BATCH / MB, 2), 512, 0, stream>>>(x, whh_hi, whh_lo, tab, hfin);
    fc_kernel<<<dim3(BATCH), 128, 0, stream>>>(hfin, W_fc, b_fc, out);
}